// Round 4
// baseline (30.069 us; speedup 1.0000x reference)
//
#include <hip/hip_runtime.h>
#include <math.h>

// Problem constants (B=256, N=32, D=D1=128, R=O=8)
#define NPAIR 64
#define NCENTER 2048     // B*R center rows
#define WCAP 64          // per-wave sublist cap (expected ~5 entries)

__device__ __forceinline__ float gelu_f(float v) {
    // exact gelu: x * 0.5 * (1 + erf(x/sqrt(2)))
    return 0.5f * v * (1.0f + erff(v * 0.70710678118654752f));
}

// One dispatch. 512 blocks = 64 pairs x 8 slices. Slice s owns batches
// b in [32s, 32s+32) for its pair: each block ballot-scans ONLY its b-range
// (1 center + 4 neighbor ballot rounds/wave), builds per-wave sublists in
// LDS (deterministic: fixed lane->id map, mbcnt prefix, no atomics), then
// runs the proven R2 GEMV loop: 4 readfirstlane'd SGPR rows (scalar x
// loads) x float2 columns from LDS, 8 fp32 FMA per d-step.
__global__ __launch_bounds__(256, 2) void fused_kernel(
    const float* __restrict__ center_h,
    const float* __restrict__ raw_neighbors,
    const float* __restrict__ Mg,
    const float* __restrict__ bias,
    const int* __restrict__ center_o,
    const int* __restrict__ s_types,
    const int* __restrict__ o_types,
    float* __restrict__ out)
{
    __shared__ float Ms[128 * 128];   // 64 KiB
    __shared__ int  list[4 * WCAP];
    __shared__ int  cnts[4];

    const int t     = threadIdx.x;
    const int wave  = t >> 6;
    const int lane  = t & 63;
    const int pair  = blockIdx.x >> 3;   // 0..63
    const int slice = blockIdx.x & 7;    // 0..7
    const int r0 = pair >> 3, o0 = pair & 7;

    // --- A1: scan loads first (retire before staging in the FIFO vmcnt queue)
    // neighbors: this block covers nid in [slice*1024, +1024); thread t holds
    // int4 #(slice*256 + t) = nids slice*1024 + t*4 .. +3
    const int4 svv = ((const int4*)s_types)[slice * 256 + t];
    const int4 ovv = ((const int4*)o_types)[slice * 256 + t];
    // centers: b in [slice*32, +32); wave w covers b = slice*32 + w*8 + (lane&7)
    const int my_b  = slice * 32 + wave * 8 + (lane & 7);
    const int my_co = center_o[my_b];

    // --- A2: async-stage M[pair] (64KB) into LDS, 16B linear global_load_lds
    const float* src = Mg + pair * 16384;
    #pragma unroll
    for (int i = 0; i < 16; ++i) {
        const int off = (t + i * 256) * 4;
        __builtin_amdgcn_global_load_lds(
            (const __attribute__((address_space(1))) void*)(src + off),
            (__attribute__((address_space(3))) void*)(&Ms[off]),
            16, 0, 0);
    }

    // --- B: ballot compaction into this wave's sublist (deterministic)
    int cw = 0;
    {   // centers: lanes 0-7 test their b
        const bool match = (lane < 8) && (my_co == o0);
        const unsigned long long mk = __ballot(match);
        const int pre = __builtin_amdgcn_mbcnt_hi(
            (unsigned)(mk >> 32), __builtin_amdgcn_mbcnt_lo((unsigned)mk, 0));
        if (match) {
            const int pos = cw + pre;
            if (pos < WCAP) list[wave * WCAP + pos] = my_b * 8 + r0;
        }
        cw += __popcll(mk);
    }
    {
        const int ss[4] = { svv.x, svv.y, svv.z, svv.w };
        const int oo[4] = { ovv.x, ovv.y, ovv.z, ovv.w };
        const int base_nid = slice * 1024 + t * 4;
        #pragma unroll
        for (int j = 0; j < 4; ++j) {
            const int s = ss[j] < 0 ? 0 : ss[j];
            const int o = oo[j] < 0 ? 0 : oo[j];
            const bool match = (s == r0) & (o == o0);
            const unsigned long long mk = __ballot(match);
            const int pre = __builtin_amdgcn_mbcnt_hi(
                (unsigned)(mk >> 32), __builtin_amdgcn_mbcnt_lo((unsigned)mk, 0));
            if (match) {
                const int pos = cw + pre;
                if (pos < WCAP) list[wave * WCAP + pos] = NCENTER + base_nid + j;
            }
            cw += __popcll(mk);
            if (cw > WCAP) cw = WCAP;
        }
    }
    if (lane == 0) cnts[wave] = cw;
    __syncthreads();   // lists visible; vmcnt drained => M fully staged

    // --- C: grouped GEMV over this block's own list, positions jj in [0,cnt)
    const int c0 = cnts[0], c1 = cnts[1], c2 = cnts[2];
    const int cnt = c0 + c1 + c2 + cnts[3];

    const float2 bv = *(const float2*)(bias + pair * 128 + lane * 2);
    float2* out2 = (float2*)out;

    for (int g = wave; g * 4 < cnt; g += 4) {
        int ids[4];
        #pragma unroll
        for (int e = 0; e < 4; ++e) {
            const int jj = g * 4 + e;
            if (jj < cnt) {
                int a = jj, sw = 0;
                if (a >= c0) { a -= c0; sw = 1;
                    if (a >= c1) { a -= c1; sw = 2;
                        if (a >= c2) { a -= c2; sw = 3; } } }
                ids[e] = list[sw * WCAP + a];   // uniform addr => LDS broadcast
            } else ids[e] = ids[0];
        }
        const int id0 = __builtin_amdgcn_readfirstlane(ids[0]);
        const int id1 = __builtin_amdgcn_readfirstlane(ids[1]);
        const int id2 = __builtin_amdgcn_readfirstlane(ids[2]);
        const int id3 = __builtin_amdgcn_readfirstlane(ids[3]);

        const float* xp0 = (id0 < NCENTER) ? center_h + (id0 >> 3) * 128
                                           : raw_neighbors + (id0 - NCENTER) * 128;
        const float* xp1 = (id1 < NCENTER) ? center_h + (id1 >> 3) * 128
                                           : raw_neighbors + (id1 - NCENTER) * 128;
        const float* xp2 = (id2 < NCENTER) ? center_h + (id2 >> 3) * 128
                                           : raw_neighbors + (id2 - NCENTER) * 128;
        const float* xp3 = (id3 < NCENTER) ? center_h + (id3 >> 3) * 128
                                           : raw_neighbors + (id3 - NCENTER) * 128;

        float2 a0 = bv, a1 = bv, a2 = bv, a3 = bv;

        #pragma unroll 8
        for (int d = 0; d < 128; ++d) {
            const float2 mv = *(const float2*)(Ms + d * 128 + lane * 2);
            const float x0 = xp0[d];
            const float x1 = xp1[d];
            const float x2 = xp2[d];
            const float x3 = xp3[d];
            a0.x = fmaf(x0, mv.x, a0.x); a0.y = fmaf(x0, mv.y, a0.y);
            a1.x = fmaf(x1, mv.x, a1.x); a1.y = fmaf(x1, mv.y, a1.y);
            a2.x = fmaf(x2, mv.x, a2.x); a2.y = fmaf(x2, mv.y, a2.y);
            a3.x = fmaf(x3, mv.x, a3.x); a3.y = fmaf(x3, mv.y, a3.y);
        }

        {
            float2 r; r.x = gelu_f(a0.x); r.y = gelu_f(a0.y);
            out2[id0 * 64 + lane] = r;
        }
        if (g * 4 + 1 < cnt) { float2 r; r.x = gelu_f(a1.x); r.y = gelu_f(a1.y); out2[id1 * 64 + lane] = r; }
        if (g * 4 + 2 < cnt) { float2 r; r.x = gelu_f(a2.x); r.y = gelu_f(a2.y); out2[id2 * 64 + lane] = r; }
        if (g * 4 + 3 < cnt) { float2 r; r.x = gelu_f(a3.x); r.y = gelu_f(a3.y); out2[id3 * 64 + lane] = r; }
    }
}

extern "C" void kernel_launch(void* const* d_in, const int* in_sizes, int n_in,
                              void* d_out, int out_size, void* d_ws, size_t ws_size,
                              hipStream_t stream) {
    const float* center_h      = (const float*)d_in[0];
    const float* raw_neighbors = (const float*)d_in[1];
    const float* M             = (const float*)d_in[2];
    const float* bias          = (const float*)d_in[3];
    const int*   center_o      = (const int*)d_in[4];
    const int*   s_types       = (const int*)d_in[5];
    const int*   o_types       = (const int*)d_in[6];
    float* out = (float*)d_out;

    fused_kernel<<<dim3(NPAIR * 8), dim3(256), 0, stream>>>(
        center_h, raw_neighbors, M, bias, center_o, s_types, o_types, out);
}

// Round 5
// 22.303 us; speedup vs baseline: 1.3482x; 1.3482x over previous
//
#include <hip/hip_runtime.h>
#include <math.h>

// Problem constants (B=256, N=32, D=D1=128, R=O=8)
#define NPAIR 64
#define NCENTER 2048     // B*R center rows
#define WCAP 48          // per-wave sublist cap (expected ~5-8 entries)
#define CHUNK 28         // x rows staged in LDS per chunk (fits 80KB/2 blocks)

__device__ __forceinline__ float gelu_f(float v) {
    // exact gelu: x * 0.5 * (1 + erf(x/sqrt(2)))
    return 0.5f * v * (1.0f + erff(v * 0.70710678118654752f));
}

#define FMA4(acc, s, m) \
    acc.x = fmaf((s), (m).x, acc.x); acc.y = fmaf((s), (m).y, acc.y); \
    acc.z = fmaf((s), (m).z, acc.z); acc.w = fmaf((s), (m).w, acc.w);

// One dispatch, 512 blocks = 64 pairs x 8 slices.
// Decode: pair = blk & 63 -> xcd = blk % 8 = pair % 8, so all 8 slices of a
// pair share one XCD's L2 (M staged from HBM once per pair, not 8x).
// Phases: A) scan loads + async M staging; B) deterministic ballot binning;
// C) chunk loop: stage x rows to LDS, then an ALL-LDS FMA loop (no per-d
// global/scalar loads -> in-order lgkmcnt, compiler can pipeline).
__global__ __launch_bounds__(256, 2) void fused_kernel(
    const float* __restrict__ center_h,
    const float* __restrict__ raw_neighbors,
    const float* __restrict__ Mg,
    const float* __restrict__ bias,
    const int* __restrict__ center_o,
    const int* __restrict__ s_types,
    const int* __restrict__ o_types,
    float* __restrict__ out)
{
    __shared__ float Ms[128 * 128];    // 64 KiB
    __shared__ float Xs[CHUNK * 128];  // 14 KiB
    __shared__ int  list[4 * WCAP];
    __shared__ int  rowid[CHUNK];
    __shared__ int  cnts[4];

    const int t     = threadIdx.x;
    const int wave  = t >> 6;
    const int lane  = t & 63;
    const int pair  = blockIdx.x & 63;   // low bits -> XCD affinity per pair
    const int slice = blockIdx.x >> 6;   // 0..7
    const int r0 = pair >> 3, o0 = pair & 7;

    // --- A1: scan loads first (FIFO vmcnt: these retire before staging)
    const int4 svv = ((const int4*)s_types)[slice * 256 + t];
    const int4 ovv = ((const int4*)o_types)[slice * 256 + t];
    const int my_b  = slice * 32 + wave * 8 + (lane & 7);
    const int my_co = center_o[my_b];

    // --- A2: async-stage M[pair] (64KB) into LDS, 16B linear global_load_lds
    const float* src = Mg + pair * 16384;
    #pragma unroll
    for (int i = 0; i < 16; ++i) {
        const int off = (t + i * 256) * 4;
        __builtin_amdgcn_global_load_lds(
            (const __attribute__((address_space(1))) void*)(src + off),
            (__attribute__((address_space(3))) void*)(&Ms[off]),
            16, 0, 0);
    }

    // --- B: ballot compaction into this wave's sublist (deterministic)
    int cw = 0;
    {   // centers: lanes 0-7 test b = slice*32 + wave*8 + lane
        const bool match = (lane < 8) && (my_co == o0);
        const unsigned long long mk = __ballot(match);
        const int pre = __builtin_amdgcn_mbcnt_hi(
            (unsigned)(mk >> 32), __builtin_amdgcn_mbcnt_lo((unsigned)mk, 0));
        if (match) {
            const int pos = cw + pre;
            if (pos < WCAP) list[wave * WCAP + pos] = my_b * 8 + r0;
        }
        cw += __popcll(mk);
    }
    {
        const int ss[4] = { svv.x, svv.y, svv.z, svv.w };
        const int oo[4] = { ovv.x, ovv.y, ovv.z, ovv.w };
        const int base_nid = slice * 1024 + t * 4;
        #pragma unroll
        for (int j = 0; j < 4; ++j) {
            const int s = ss[j] < 0 ? 0 : ss[j];
            const int o = oo[j] < 0 ? 0 : oo[j];
            const bool match = (s == r0) & (o == o0);
            const unsigned long long mk = __ballot(match);
            const int pre = __builtin_amdgcn_mbcnt_hi(
                (unsigned)(mk >> 32), __builtin_amdgcn_mbcnt_lo((unsigned)mk, 0));
            if (match) {
                const int pos = cw + pre;
                if (pos < WCAP) list[wave * WCAP + pos] = NCENTER + base_nid + j;
            }
            cw += __popcll(mk);
            if (cw > WCAP) cw = WCAP;
        }
    }
    if (lane == 0) cnts[wave] = cw;
    __syncthreads();   // lists visible; vmcnt drained => M fully staged

    const int c0 = cnts[0], c1 = cnts[1], c2 = cnts[2];
    const int cnt = c0 + c1 + c2 + cnts[3];

    const int lh   = lane & 31;   // lane-in-half: owns cols lh*4..lh*4+3
    const int half = lane >> 5;   // half-wave row-group selector
    const float4 bv = *(const float4*)(bias + pair * 128 + lh * 4);
    float4* out4 = (float4*)out;

    for (int base = 0; base < cnt; base += CHUNK) {
        const int csz = (cnt - base < CHUNK) ? (cnt - base) : CHUNK;

        // decode this chunk's global row ids into rowid[] (threads 0..CHUNK-1)
        if (t < CHUNK) {
            int id = 0;
            if (t < csz) {
                int a = base + t, sw = 0;
                if (a >= c0) { a -= c0; sw = 1;
                    if (a >= c1) { a -= c1; sw = 2;
                        if (a >= c2) { a -= c2; sw = 3; } } }
                id = list[sw * WCAP + a];
            }
            rowid[t] = id;
        }
        __syncthreads();

        // stage chunk x rows into LDS (coalesced: 32 consecutive threads/row)
        for (int i = t; i < csz * 32; i += 256) {
            const int r = i >> 5, g = i & 31;
            const int id = rowid[r];
            const float4* xp = (id < NCENTER)
                ? (const float4*)(center_h + (id >> 3) * 128)
                : (const float4*)(raw_neighbors + (id - NCENTER) * 128);
            ((float4*)Xs)[r * 32 + g] = xp[g];
        }
        __syncthreads();

        // compute: wave w, half h handles chunk rows 8w+4h .. +3 (clamped)
        const int rbase = 8 * wave + 4 * half;
        if (rbase < csz) {
            const int rr1 = (rbase + 1 < csz) ? rbase + 1 : csz - 1;
            const int rr2 = (rbase + 2 < csz) ? rbase + 2 : csz - 1;
            const int rr3 = (rbase + 3 < csz) ? rbase + 3 : csz - 1;
            const float* x0 = Xs + rbase * 128;
            const float* x1 = Xs + rr1 * 128;
            const float* x2 = Xs + rr2 * 128;
            const float* x3 = Xs + rr3 * 128;

            float4 a0 = bv, a1 = bv, a2 = bv, a3 = bv;

            #pragma unroll 2
            for (int d = 0; d < 128; d += 4) {
                const float4 xv0 = *(const float4*)(x0 + d);
                const float4 xv1 = *(const float4*)(x1 + d);
                const float4 xv2 = *(const float4*)(x2 + d);
                const float4 xv3 = *(const float4*)(x3 + d);
                const float4 m0 = *(const float4*)(Ms + (d + 0) * 128 + lh * 4);
                const float4 m1 = *(const float4*)(Ms + (d + 1) * 128 + lh * 4);
                const float4 m2 = *(const float4*)(Ms + (d + 2) * 128 + lh * 4);
                const float4 m3 = *(const float4*)(Ms + (d + 3) * 128 + lh * 4);
                FMA4(a0, xv0.x, m0); FMA4(a0, xv0.y, m1);
                FMA4(a0, xv0.z, m2); FMA4(a0, xv0.w, m3);
                FMA4(a1, xv1.x, m0); FMA4(a1, xv1.y, m1);
                FMA4(a1, xv1.z, m2); FMA4(a1, xv1.w, m3);
                FMA4(a2, xv2.x, m0); FMA4(a2, xv2.y, m1);
                FMA4(a2, xv2.z, m2); FMA4(a2, xv2.w, m3);
                FMA4(a3, xv3.x, m0); FMA4(a3, xv3.y, m1);
                FMA4(a3, xv3.z, m2); FMA4(a3, xv3.w, m3);
            }

            {
                float4 r; r.x = gelu_f(a0.x); r.y = gelu_f(a0.y);
                r.z = gelu_f(a0.z); r.w = gelu_f(a0.w);
                out4[rowid[rbase] * 32 + lh] = r;
            }
            if (rbase + 1 < csz) {
                float4 r; r.x = gelu_f(a1.x); r.y = gelu_f(a1.y);
                r.z = gelu_f(a1.z); r.w = gelu_f(a1.w);
                out4[rowid[rr1] * 32 + lh] = r;
            }
            if (rbase + 2 < csz) {
                float4 r; r.x = gelu_f(a2.x); r.y = gelu_f(a2.y);
                r.z = gelu_f(a2.z); r.w = gelu_f(a2.w);
                out4[rowid[rr2] * 32 + lh] = r;
            }
            if (rbase + 3 < csz) {
                float4 r; r.x = gelu_f(a3.x); r.y = gelu_f(a3.y);
                r.z = gelu_f(a3.z); r.w = gelu_f(a3.w);
                out4[rowid[rr3] * 32 + lh] = r;
            }
        }
        __syncthreads();  // Xs reused next chunk
    }
}

extern "C" void kernel_launch(void* const* d_in, const int* in_sizes, int n_in,
                              void* d_out, int out_size, void* d_ws, size_t ws_size,
                              hipStream_t stream) {
    const float* center_h      = (const float*)d_in[0];
    const float* raw_neighbors = (const float*)d_in[1];
    const float* M             = (const float*)d_in[2];
    const float* bias          = (const float*)d_in[3];
    const int*   center_o      = (const int*)d_in[4];
    const int*   s_types       = (const int*)d_in[5];
    const int*   o_types       = (const int*)d_in[6];
    float* out = (float*)d_out;

    fused_kernel<<<dim3(NPAIR * 8), dim3(256), 0, stream>>>(
        center_h, raw_neighbors, M, bias, center_o, s_types, o_types, out);
}

// Round 6
// 12.545 us; speedup vs baseline: 2.3970x; 1.7779x over previous
//
#include <hip/hip_runtime.h>
#include <math.h>

// Problem constants (B=256, N=32, D=D1=128, R=O=8)
#define NPAIR 64
#define NCENTER 2048
#define WCAP 48
#define RSLOT 32   // rows per MFMA chunk (2 row-tiles of 16)

typedef __attribute__((ext_vector_type(8))) short bfrag8;        // 8 bf16 (4 VGPR)
typedef __attribute__((ext_vector_type(8))) unsigned short u16x8;
typedef __attribute__((ext_vector_type(4))) float f32x4;

__device__ __forceinline__ float gelu_f(float v) {
    return 0.5f * v * (1.0f + erff(v * 0.70710678118654752f));
}
// fp32 -> bf16 round-to-nearest-even
__device__ __forceinline__ unsigned short f2bf(float f) {
    unsigned int u = __float_as_uint(f);
    return (unsigned short)((u + 0x7FFFu + ((u >> 16) & 1u)) >> 16);
}

// 512 blocks = 64 pairs x 8 slices (pair = blk&63 -> XCD L2 affinity).
// Phases: A) scan loads; M fp32->bf16 in-register 8x8 transpose -> LDS [c][d]
// (XOR-swizzled 16B chunks, conflict-free both sides); B) deterministic ballot
// binning; C) per 32-row chunk: stage x rows bf16 (swizzled), then
// mfma_f32_16x16x32_bf16: per wave 2 col-tiles x 2 row-tiles x 4 k-steps.
__global__ __launch_bounds__(256) void fused_kernel(
    const float* __restrict__ center_h,
    const float* __restrict__ raw_neighbors,
    const float* __restrict__ Mg,
    const float* __restrict__ bias,
    const int* __restrict__ center_o,
    const int* __restrict__ s_types,
    const int* __restrict__ o_types,
    float* __restrict__ out)
{
    __shared__ __align__(16) unsigned short Mbt[128 * 128];  // 32 KB, [c][d] swizzled
    __shared__ __align__(16) unsigned short Xs[RSLOT * 128]; // 8 KB, [row][d] swizzled
    __shared__ int list[4 * WCAP];
    __shared__ int cnts[4];
    __shared__ int rowid[RSLOT];

    const int t    = threadIdx.x;
    const int wave = t >> 6, lane = t & 63;
    const int pair = blockIdx.x & 63, slice = blockIdx.x >> 6;
    const int r0 = pair >> 3, o0 = pair & 7;

    // --- A1: scan loads
    const int4 svv = ((const int4*)s_types)[slice * 256 + t];
    const int4 ovv = ((const int4*)o_types)[slice * 256 + t];
    const int my_b  = slice * 32 + wave * 8 + (lane & 7);
    const int my_co = center_o[my_b];

    // --- A2: M -> bf16, transposed into LDS [c][d] with chunk XOR swizzle.
    // thread (dblk=t>>4, cblk=t&15) handles the 8x8 block (d,c) =
    // (dblk*8..+7, cblk*8..+7). Reads coalesced; writes b128 conflict-free.
    {
        const int dblk = t >> 4, cblk = t & 15;
        const float* bp = Mg + pair * 16384 + dblk * 8 * 128 + cblk * 8;
        float gg[8][8];
        #pragma unroll
        for (int r = 0; r < 8; ++r) {
            const float4 x0 = *(const float4*)(bp + r * 128);
            const float4 x1 = *(const float4*)(bp + r * 128 + 4);
            gg[r][0] = x0.x; gg[r][1] = x0.y; gg[r][2] = x0.z; gg[r][3] = x0.w;
            gg[r][4] = x1.x; gg[r][5] = x1.y; gg[r][6] = x1.z; gg[r][7] = x1.w;
        }
        #pragma unroll
        for (int i = 0; i < 8; ++i) {
            u16x8 w;
            #pragma unroll
            for (int j = 0; j < 8; ++j) w[j] = f2bf(gg[j][i]);
            const int c  = cblk * 8 + i;
            const int sl = (dblk ^ (cblk & 7) ^ i) << 4;   // = dch ^ ((c>>3)&7) ^ (c&7)
            *(u16x8*)((char*)Mbt + c * 256 + sl) = w;
        }
    }

    // --- B: ballot compaction (deterministic, proven R5)
    int cw = 0;
    {
        const bool match = (lane < 8) && (my_co == o0);
        const unsigned long long mk = __ballot(match);
        const int pre = __builtin_amdgcn_mbcnt_hi(
            (unsigned)(mk >> 32), __builtin_amdgcn_mbcnt_lo((unsigned)mk, 0));
        if (match) {
            const int pos = cw + pre;
            if (pos < WCAP) list[wave * WCAP + pos] = my_b * 8 + r0;
        }
        cw += __popcll(mk);
    }
    {
        const int ss[4] = { svv.x, svv.y, svv.z, svv.w };
        const int oo[4] = { ovv.x, ovv.y, ovv.z, ovv.w };
        const int base_nid = slice * 1024 + t * 4;
        #pragma unroll
        for (int j = 0; j < 4; ++j) {
            const int s = ss[j] < 0 ? 0 : ss[j];
            const int o = oo[j] < 0 ? 0 : oo[j];
            const bool match = (s == r0) & (o == o0);
            const unsigned long long mk = __ballot(match);
            const int pre = __builtin_amdgcn_mbcnt_hi(
                (unsigned)(mk >> 32), __builtin_amdgcn_mbcnt_lo((unsigned)mk, 0));
            if (match) {
                const int pos = cw + pre;
                if (pos < WCAP) list[wave * WCAP + pos] = NCENTER + base_nid + j;
            }
            cw += __popcll(mk);
            if (cw > WCAP) cw = WCAP;
        }
    }
    if (lane == 0) cnts[wave] = cw;
    __syncthreads();   // lists + Mbt visible

    const int c0_ = cnts[0], c1_ = cnts[1], c2_ = cnts[2];
    const int cnt = c0_ + c1_ + c2_ + cnts[3];

    const int lo16 = lane & 15, hi4 = lane >> 4;
    const int cA = wave * 32 + lo16;     // col-tile 2*wave
    const int cB = cA + 16;              // col-tile 2*wave+1
    const float bvA = bias[pair * 128 + cA];
    const float bvB = bias[pair * 128 + cB];
    const int keyA = ((cA >> 3) & 7) ^ (cA & 7);
    const int keyB = ((cB >> 3) & 7) ^ (cB & 7);
    const int rsw  = lo16 & 7;           // row-swizzle key (rt*16+lo16)&7

    for (int base = 0; base < cnt; base += RSLOT) {
        const int csz = (cnt - base < RSLOT) ? (cnt - base) : RSLOT;

        if (t < RSLOT) {
            int id = -1;
            int a = base + t;
            if (a < cnt) {
                int sw = 0;
                if (a >= c0_) { a -= c0_; sw = 1;
                    if (a >= c1_) { a -= c1_; sw = 2;
                        if (a >= c2_) { a -= c2_; sw = 3; } } }
                id = list[sw * WCAP + a];
            }
            rowid[t] = id;
        }
        __syncthreads();   // rowid visible

        // stage x rows (bf16, swizzled); pad rows = zeros
        #pragma unroll
        for (int i = 0; i < 2; ++i) {
            const int flat = i * 256 + t;      // 0..511 = 32 rows x 16 chunks
            const int row = flat >> 4, ch = flat & 15;
            const int id = rowid[row];
            u16x8 w = {0, 0, 0, 0, 0, 0, 0, 0};
            if (id >= 0) {
                const float* xp = (id < NCENTER) ? center_h + (id >> 3) * 128
                                                 : raw_neighbors + (id - NCENTER) * 128;
                const float4 x0 = *(const float4*)(xp + ch * 8);
                const float4 x1 = *(const float4*)(xp + ch * 8 + 4);
                w[0] = f2bf(x0.x); w[1] = f2bf(x0.y); w[2] = f2bf(x0.z); w[3] = f2bf(x0.w);
                w[4] = f2bf(x1.x); w[5] = f2bf(x1.y); w[6] = f2bf(x1.z); w[7] = f2bf(x1.w);
            }
            *(u16x8*)((char*)Xs + row * 256 + ((ch ^ (row & 7)) << 4)) = w;
        }
        __syncthreads();   // Xs visible

        // MFMA: A row = lane&15, k = (lane>>4)*8+j ; B same K pattern from Mbt[c][d]
        f32x4 accA = {bvA, bvA, bvA, bvA};
        f32x4 accB = {bvB, bvB, bvB, bvB};
        f32x4 accC = accA, accD = accB;
        const int rowA = lo16, rowB = 16 + lo16;
        #pragma unroll
        for (int k = 0; k < 4; ++k) {
            const int dch = 4 * k + hi4;    // 16B chunk = 8 consecutive d
            const bfrag8 aA = *(const bfrag8*)((const char*)Xs  + rowA * 256 + ((dch ^ rsw)  << 4));
            const bfrag8 aB = *(const bfrag8*)((const char*)Xs  + rowB * 256 + ((dch ^ rsw)  << 4));
            const bfrag8 b0 = *(const bfrag8*)((const char*)Mbt + cA   * 256 + ((dch ^ keyA) << 4));
            const bfrag8 b1 = *(const bfrag8*)((const char*)Mbt + cB   * 256 + ((dch ^ keyB) << 4));
            accA = __builtin_amdgcn_mfma_f32_16x16x32_bf16(aA, b0, accA, 0, 0, 0);
            accB = __builtin_amdgcn_mfma_f32_16x16x32_bf16(aA, b1, accB, 0, 0, 0);
            accC = __builtin_amdgcn_mfma_f32_16x16x32_bf16(aB, b0, accC, 0, 0, 0);
            accD = __builtin_amdgcn_mfma_f32_16x16x32_bf16(aB, b1, accD, 0, 0, 0);
        }

        // epilogue: D col = lane&15 (-> cA/cB), row = (lane>>4)*4 + j (-> slot)
        #pragma unroll
        for (int j = 0; j < 4; ++j) {
            const int sA = hi4 * 4 + j;
            if (sA < csz) {
                const int gid = rowid[sA];
                out[gid * 128 + cA] = gelu_f(accA[j]);
                out[gid * 128 + cB] = gelu_f(accB[j]);
            }
            const int sB = 16 + hi4 * 4 + j;
            if (sB < csz) {
                const int gid = rowid[sB];
                out[gid * 128 + cA] = gelu_f(accC[j]);
                out[gid * 128 + cB] = gelu_f(accD[j]);
            }
        }
        __syncthreads();   // protect Xs/rowid before next chunk
    }
}

extern "C" void kernel_launch(void* const* d_in, const int* in_sizes, int n_in,
                              void* d_out, int out_size, void* d_ws, size_t ws_size,
                              hipStream_t stream) {
    const float* center_h      = (const float*)d_in[0];
    const float* raw_neighbors = (const float*)d_in[1];
    const float* M             = (const float*)d_in[2];
    const float* bias          = (const float*)d_in[3];
    const int*   center_o      = (const int*)d_in[4];
    const int*   s_types       = (const int*)d_in[5];
    const int*   o_types       = (const int*)d_in[6];
    float* out = (float*)d_out;

    fused_kernel<<<dim3(NPAIR * 8), dim3(256), 0, stream>>>(
        center_h, raw_neighbors, M, bias, center_o, s_types, o_types, out);
}